// Round 18
// baseline (192.178 us; speedup 1.0000x reference)
//
#include <hip/hip_runtime.h>

#define HH 80
#define WW 80
#define BB 4
#define NPIX (BB*HH*WW)
#define AS1 __attribute__((address_space(1)))
#define AS3 __attribute__((address_space(3)))

typedef _Float16 f16;
typedef _Float16 f16x8 __attribute__((ext_vector_type(8)));
typedef float    f32x4 __attribute__((ext_vector_type(4)));
typedef unsigned int uint;
typedef unsigned short ushort;

__device__ inline f16x8 splat8(uint u) {
    uint4 q = {u, u, u, u};
    return __builtin_bit_cast(f16x8, q);
}
__device__ inline ushort h_bits(float w) {
    f16 h = (f16)w;
    return __builtin_bit_cast(ushort, h);
}
__device__ inline int swiz400(int m)  { return (m & 7) * 50  + (m >> 3); }
__device__ inline int swiz1600(int m) { return (m & 7) * 200 + (m >> 3); }

// ---------------- fused weight-prep: 7 MFMA-B packs + 4 depthwise f16 transposes --------
struct PrepDesc {
    const float* src; f16* dst;
    int cout, cin, kk2, nt_tot, total, mode;  // mode 0 = MFMA pack, 1 = dwT f16 (kk2 = K)
};
struct PrepArgs { PrepDesc d[11]; int grand_total; };

__global__ void prep_k(PrepArgs P) {
    for (int idx = blockIdx.x * 256 + threadIdx.x; idx < P.grand_total;
         idx += gridDim.x * 256) {
        int i = 0, base = 0;
        while (idx >= base + P.d[i].total) { base += P.d[i].total; i++; }
        const PrepDesc& D = P.d[i];
        int e = idx - base;
        if (D.mode == 0) {
            int j  = e & 7;
            int l  = (e >> 3) & 63;
            int rr = e >> 9;
            int ct = rr % D.nt_tot;
            int ks = rr / D.nt_tot;
            int kkk = ks * 32 + (l >> 4) * 8 + j;
            int tap = kkk / D.cin;
            int ci  = kkk % D.cin;
            int n = ct * 16 + (l & 15);
            float v = (n < D.cout) ? D.src[((size_t)n * D.cin + ci) * D.kk2 + tap] : 0.f;
            D.dst[e] = (f16)v;
        } else {
            int o = e & 63, tt = e >> 6;
            D.dst[e] = (f16)D.src[o * D.kk2 + tt];
        }
    }
}

// ---------------- x (NCHW f32) -> xb (NHWC f16) ----------------
__global__ void xcvt_k(const float* __restrict__ x, f16* __restrict__ xb) {
    __shared__ float l[128 * 17];
    int t = threadIdx.x;
    int blk = blockIdx.x;
    int wb = blk % 5;
    int r  = blk / 5;
    int h  = r % HH;
    int b  = r / HH;
    int w0 = wb * 16;
    size_t pixbase = (size_t)(b * HH + h) * WW + w0;
    for (int e = t; e < 2048; e += 256) {
        int c = e >> 4, p = e & 15;
        l[c * 17 + p] = x[((size_t)(b * 128 + c)) * (HH * WW) + h * WW + w0 + p];
    }
    __syncthreads();
    for (int e = t; e < 2048; e += 256) {
        int c = e & 127, p = e >> 7;
        xb[(pixbase + p) * 128 + c] = (f16)l[c * 17 + p];
    }
}

// ---------------- MFMA implicit-GEMM conv: BM=64 tile, 2-phase gload_lds dbuf ----------
// 4 waves x (1 M-frag x NT); LDS 32KB -> 5 blocks/CU; grid 2x vs BM=128.
struct MArgs {
    const f16* in; const f16* wp; const float* bias;
    float* outf; f16* outh;
    const float* bn_g; const float* bn_b; const float* bn_m; const float* bn_v;
    const f16* zbuf;
    int cin_tot, ci_base, nt_tot, cout, out_stride, pad, dil;
};

template<int K, int CIN, int NT, bool OUT_F16, bool BNSILU>
__device__ __forceinline__ void mconv_body(int bx, int by, char* lds, const MArgs& A) {
    constexpr int NST  = K * K * CIN / 64;   // stages
    constexpr int AF16 = 4096;               // A f16 per buf (64px x 64ch)
    constexpr int BF16 = NT * 1024;          // B f16 per buf (2 ksteps x NT x 512)
    f16* Al = (f16*)lds;
    f16* Bl = (f16*)(lds + 2 * AF16 * 2);
    const int t    = threadIdx.x;
    const int lane = t & 63;
    const int wv   = t >> 6;
    const int blkpix = bx * 64;
    const int ntb    = by * NT;

    auto stage = [&](int s, int buf) {
        int tap, ch0;
        if constexpr (CIN == 64) { tap = s; ch0 = 0; }
        else                     { tap = s >> 1; ch0 = (s & 1) * 64; }
        int ky = tap / K, kx = tap - ky * K;
        int g    = t & 7;
        int prel = t >> 3;                   // 0..31
#pragma unroll
        for (int i = 0; i < 2; i++) {
            int pl  = prel + i * 32;
            int pix = blkpix + pl;
            int b   = pix / 6400;
            int rem = pix - b * 6400;
            int h = rem / WW, w = rem - h * WW;
            int y = h + ky * A.dil - A.pad;
            int x = w + kx * A.dil - A.pad;
            bool v = ((unsigned)y < (unsigned)HH) & ((unsigned)x < (unsigned)WW);
            int sg = g ^ (pl & 7);
            const f16* src = v
                ? A.in + ((size_t)(b * 6400 + y * WW + x)) * A.cin_tot + A.ci_base + ch0 + sg * 8
                : A.zbuf + sg * 8;
            __builtin_amdgcn_global_load_lds((const AS1 void*)src,
                (AS3 void*)(Al + buf * AF16 + i * 2048 + t * 8), 16, 0, 0);
        }
        if constexpr (NT == 4) {
#pragma unroll
            for (int j = 0; j < 2; j++) {
                const f16* src = A.wp + ((size_t)(2 * s + j) * A.nt_tot + ntb) * 512 + t * 8;
                __builtin_amdgcn_global_load_lds((const AS1 void*)src,
                    (AS3 void*)(Bl + buf * BF16 + j * 2048 + t * 8), 16, 0, 0);
            }
        } else {   // NT==2, nt_tot==2, ntb==0
            const f16* src = A.wp + (size_t)(2 * s) * A.nt_tot * 512 + t * 8;
            __builtin_amdgcn_global_load_lds((const AS1 void*)src,
                (AS3 void*)(Bl + buf * BF16 + t * 8), 16, 0, 0);
        }
    };

    f32x4 acc[NT];
#pragma unroll
    for (int n = 0; n < NT; n++) acc[n] = (f32x4){0.f, 0.f, 0.f, 0.f};

    auto compute = [&](int buf) {
#pragma unroll
        for (int j = 0; j < 2; j++) {
            f16x8 bfr[NT];
#pragma unroll
            for (int n = 0; n < NT; n++)
                bfr[n] = *(const f16x8*)(Bl + buf * BF16 + j * NT * 512 + n * 512 + lane * 8);
            int px = wv * 16 + (lane & 15);
            int gi = (j * 4 + (lane >> 4)) ^ (px & 7);
            f16x8 a = *(const f16x8*)(Al + buf * AF16 + px * 64 + gi * 8);
#pragma unroll
            for (int n = 0; n < NT; n++)
                acc[n] = __builtin_amdgcn_mfma_f32_16x16x32_f16(a, bfr[n], acc[n], 0, 0, 0);
        }
    };

    stage(0, 0);
    __syncthreads();
    for (int s = 0; s < NST; s++) {
        int buf = s & 1;
        if (s + 1 < NST) stage(s + 1, buf ^ 1);
        compute(buf);
        __syncthreads();
    }

    const int nloc = lane & 15;
    const int prow = blkpix + wv * 16 + (lane >> 4) * 4;
#pragma unroll
    for (int ct = 0; ct < NT; ct++) {
        int n = (ntb + ct) * 16 + nloc;
        if (n >= A.cout) continue;
        float sc = 1.f, sh = 0.f, bv = 0.f;
        if (BNSILU) {
            sc = A.bn_g[n] / sqrtf(A.bn_v[n] + 1e-5f);
            sh = A.bn_b[n] - A.bn_m[n] * sc;
        } else if (A.bias) {
            bv = A.bias[n];
        }
#pragma unroll
        for (int r = 0; r < 4; r++) {
            float vv = acc[ct][r] + bv;
            if (BNSILU) { vv = vv * sc + sh; vv = vv / (1.f + expf(-vv)); }
            size_t o = (size_t)(prow + r) * A.out_stride + n;
            if (OUT_F16) A.outh[o] = (f16)vv; else A.outf[o] = vv;
        }
    }
}

__global__ __launch_bounds__(256, 4) void mconv_main_k(MArgs A) {
    __shared__ char lds[2 * 8192 + 2 * 8192];
    int b = blockIdx.x;
    mconv_body<3, 128, 4, true, true>(swiz400(b % 400), b / 400, lds, A);
}

// interleaved pair: every (R+1)-th block runs A1
template<int K1, int C1, int N1, int K2, int C2, int N2, int R>
__global__ __launch_bounds__(256, 4) void mconv_pair_k(MArgs A1, MArgs A2) {
    constexpr int MAXNT = (N1 > N2) ? N1 : N2;
    __shared__ char lds[2 * 8192 + 2 * MAXNT * 2048];
    int b = blockIdx.x;
    int q = b / (R + 1), m = b - q * (R + 1);
    if (m == R) {
        mconv_body<K1, C1, N1, false, false>(swiz400(q % 400), q / 400, lds, A1);
    } else {
        int idx = q * R + m;
        mconv_body<K2, C2, N2, false, false>(swiz400(idx % 400), idx / 400, lds, A2);
    }
}

// ---------------- deformable sample: R17 body (dw staged in LDS) ----------
struct DArgs {
    const f16* in; const float* off; const f16* dwh; f16* out;
    int csh, ci_base, off_stride;
};
struct alignas(16) DEnt { int o00; short dx1, dy1; uint w01, w23; };

template<int KS, int PAD, int DIL>
__device__ __forceinline__ void dsample_body(int blk, char* ldsraw, const DArgs A) {
    constexpr int K = KS * KS;
    DEnt* ent = (DEnt*)ldsraw;
    f16*  dwl = (f16*)(ldsraw + 16 * K * 16);
    const int t = threadIdx.x;   // 0..127

    for (int e = t; e < 16 * K; e += 128) {
        int p  = e / K;
        int kk = e - p * K;
        int pix = blk * 16 + p;
        int b   = pix / (HH * WW);
        int rem = pix - b * (HH * WW);
        int h   = rem / WW;
        int w   = rem - h * WW;
        int ky = kk / KS, kx = kk - ky * KS;
        float2 d = *(const float2*)&A.off[(size_t)pix * A.off_stride + 2 * kk];
        float py = (float)(h + ky * DIL - PAD) + d.x;
        float px = (float)(w + kx * DIL - PAD) + d.y;
        float y0f = floorf(py), x0f = floorf(px);
        float ty = py - y0f, tx = px - x0f;
        int iy0 = (int)y0f, ix0 = (int)x0f;
        bool vy0 = (unsigned)iy0 < (unsigned)HH;
        bool vy1 = (unsigned)(iy0 + 1) < (unsigned)HH;
        bool vx0 = (unsigned)ix0 < (unsigned)WW;
        bool vx1 = (unsigned)(ix0 + 1) < (unsigned)WW;
        int cy0 = min(max(iy0, 0), HH - 1), cy1 = min(max(iy0 + 1, 0), HH - 1);
        int cx0 = min(max(ix0, 0), WW - 1), cx1 = min(max(ix0 + 1, 0), WW - 1);
        float wy0 = 1.f - ty, wx0 = 1.f - tx;
        ushort w00 = h_bits(wy0 * wx0 * ((vy0 && vx0) ? 1.f : 0.f));
        ushort w01 = h_bits(wy0 * tx  * ((vy0 && vx1) ? 1.f : 0.f));
        ushort w10 = h_bits(ty  * wx0 * ((vy1 && vx0) ? 1.f : 0.f));
        ushort w11 = h_bits(ty  * tx  * ((vy1 && vx1) ? 1.f : 0.f));
        DEnt E;
        E.o00 = (b * (HH * WW) + cy0 * WW + cx0) << A.csh;
        E.dx1 = (short)((cx1 - cx0) << A.csh);
        E.dy1 = (short)(((cy1 - cy0) * WW) << A.csh);
        E.w01 = (uint)w00 | ((uint)w01 << 16);
        E.w23 = (uint)w10 | ((uint)w11 << 16);
        ent[e] = E;
    }
    for (int e = t; e < K * 8; e += 128)
        ((f16x8*)dwl)[e] = ((const f16x8*)A.dwh)[e];
    __syncthreads();

    const int li  = t & 7;
    const int p   = t >> 3;      // 0..15
    const int ch0 = li * 8;
    const int pix = blk * 16 + p;
    const char* ibase = (const char*)(A.in + A.ci_base) + ch0 * 2;
    const f16*  dwb  = dwl + ch0;

    float acc[8];
#pragma unroll
    for (int j = 0; j < 8; j++) acc[j] = 0.f;

#pragma unroll 4
    for (int kk = 0; kk < K; kk++) {
        DEnt e = ent[p * K + kk];
        uint s00 = (e.w01 & 0xffffu) * 0x10001u;
        uint s01 = (e.w01 >> 16)     * 0x10001u;
        uint s10 = (e.w23 & 0xffffu) * 0x10001u;
        uint s11 = (e.w23 >> 16)     * 0x10001u;
        int o00 = e.o00, o01 = o00 + e.dx1, o10 = o00 + e.dy1, o11 = o10 + e.dx1;
        f16x8 c00 = *(const f16x8*)(ibase + o00);
        f16x8 c01 = *(const f16x8*)(ibase + o01);
        f16x8 c10 = *(const f16x8*)(ibase + o10);
        f16x8 c11 = *(const f16x8*)(ibase + o11);
        f16x8 s = c00 * splat8(s00);
        s = c01 * splat8(s01) + s;
        s = c10 * splat8(s10) + s;
        s = c11 * splat8(s11) + s;
        f16x8 dw = *(const f16x8*)(dwb + kk * 64);
#pragma unroll
        for (int j = 0; j < 8; j++)
            acc[j] = fmaf((float)dw[j], (float)s[j], acc[j]);   // v_fma_mix_f32
    }

    f16x8 o;
#pragma unroll
    for (int j = 0; j < 8; j++) o[j] = (f16)acc[j];
    *(f16x8*)&A.out[(size_t)pix * 64 + ch0] = o;
}

// sequential halves: each phase keeps one branch's tensors XCD-resident
template<int K1, int P1, int D1, int K2, int P2, int D2>
__global__ __launch_bounds__(128, 4) void dsample_pair_k(DArgs A1, int nblk1, DArgs A2) {
    constexpr int KMAX = (K1 * K1 > K2 * K2) ? K1 * K1 : K2 * K2;
    __shared__ char lds[16 * KMAX * 16 + KMAX * 128];
    int b = blockIdx.x;
    if (b < nblk1) dsample_body<K1, P1, D1>(swiz1600(b), lds, A1);
    else           dsample_body<K2, P2, D2>(swiz1600(b - nblk1), lds, A2);
}

// ---------------- final: out(NCHW) = x + u*attn ----------------
__global__ void final_k(const float* __restrict__ x, const f16* __restrict__ u,
                        const float* __restrict__ af, const float* __restrict__ bf,
                        float* __restrict__ out) {
    __shared__ float lu[16 * 130];
    __shared__ float lat[16 * 130];
    int t   = threadIdx.x;
    int blk = blockIdx.x;
    int wb = blk % 5;
    int r  = blk / 5;
    int h  = r % HH;
    int b  = r / HH;
    int w0 = wb * 16;
    size_t pixbase = (size_t)(b * HH + h) * WW + w0;
    for (int e = t; e < 16 * 128; e += 256) {
        int c = e & 127;
        int p = e >> 7;
        lu[p * 130 + c]  = (float)u[(pixbase + p) * 128 + c];
        lat[p * 130 + c] = (c < 64) ? af[(pixbase + p) * 64 + c]
                                    : bf[(pixbase + p) * 64 + (c - 64)];
    }
    __syncthreads();
    for (int e = t; e < 16 * 128; e += 256) {
        int p = e & 15;
        int c = e >> 4;
        size_t gi = ((size_t)(b * 128 + c) * HH + h) * WW + w0 + p;
        out[gi] = x[gi] + lu[p * 130 + c] * lat[p * 130 + c];
    }
}

extern "C" void kernel_launch(void* const* d_in, const int* in_sizes, int n_in,
                              void* d_out, int out_size, void* d_ws, size_t ws_size,
                              hipStream_t stream) {
    const float* x        = (const float*)d_in[0];
    const float* cv1_w    = (const float*)d_in[1];
    const float* bn_g     = (const float*)d_in[2];
    const float* bn_b     = (const float*)d_in[3];
    const float* bn_m     = (const float*)d_in[4];
    const float* bn_v     = (const float*)d_in[5];
    const float* a0_off_w = (const float*)d_in[6];
    const float* a0_off_b = (const float*)d_in[7];
    const float* a0_w     = (const float*)d_in[8];
    const float* a1_off_w = (const float*)d_in[9];
    const float* a1_off_b = (const float*)d_in[10];
    const float* a1_w     = (const float*)d_in[11];
    const float* b0_off_w = (const float*)d_in[12];
    const float* b0_off_b = (const float*)d_in[13];
    const float* b0_w     = (const float*)d_in[14];
    const float* b1_off_w = (const float*)d_in[15];
    const float* b1_off_b = (const float*)d_in[16];
    const float* b1_w     = (const float*)d_in[17];
    const float* conv1_w  = (const float*)d_in[18];
    const float* conv1_b  = (const float*)d_in[19];
    const float* conv2_w  = (const float*)d_in[20];
    const float* conv2_b  = (const float*)d_in[21];
    float* out = (float*)d_out;

    char* wsb = (char*)d_ws;
    size_t pos = 0;
    auto alloc = [&](size_t bytes) -> void* {
        void* p = (void*)(wsb + pos);
        pos += (bytes + 255) & ~(size_t)255;
        return p;
    };
    f16*   zbuf   = (f16*)  alloc(256);
    f16*   xb     = (f16*)  alloc((size_t)NPIX * 128 * 2);
    f16*   u      = (f16*)  alloc((size_t)NPIX * 128 * 2);
    f16*   s0a    = (f16*)  alloc((size_t)NPIX * 64 * 2);
    f16*   s0b    = (f16*)  alloc((size_t)NPIX * 64 * 2);
    f16*   s1a    = (f16*)  alloc((size_t)NPIX * 64 * 2);
    f16*   s1b    = (f16*)  alloc((size_t)NPIX * 64 * 2);
    float* offa   = (float*)alloc((size_t)NPIX * 64 * 4);   // aliased: aF after offa dead
    float* offb   = (float*)alloc((size_t)NPIX * 128 * 4);  // aliased: bF after offb dead
    float* aF     = offa;
    float* bF     = offb;
    f16*   pcv1   = (f16*)  alloc((size_t)36 * 8 * 512 * 2);
    f16*   pa0    = (f16*)  alloc((size_t)18 * 2 * 512 * 2);
    f16*   pa1    = (f16*)  alloc((size_t)50 * 4 * 512 * 2);
    f16*   pb0    = (f16*)  alloc((size_t)50 * 4 * 512 * 2);
    f16*   pb1    = (f16*)  alloc((size_t)98 * 8 * 512 * 2);
    f16*   pc1    = (f16*)  alloc((size_t)2  * 4 * 512 * 2);
    f16*   pc2    = (f16*)  alloc((size_t)2  * 4 * 512 * 2);
    f16*   dwh_a0 = (f16*)  alloc(9  * 64 * 2);
    f16*   dwh_a1 = (f16*)  alloc(25 * 64 * 2);
    f16*   dwh_b0 = (f16*)  alloc(25 * 64 * 2);
    f16*   dwh_b1 = (f16*)  alloc(49 * 64 * 2);

    hipMemsetAsync(zbuf, 0, 256, stream);
    xcvt_k<<<dim3(BB * HH * 5), dim3(256), 0, stream>>>(x, xb);

    // fused weight prep
    PrepArgs P;
    int gt = 0, di = 0;
    auto addpk = [&](const float* src, f16* dst, int cout, int cin, int kk2, int nt, int nk) {
        PrepDesc D; D.src = src; D.dst = dst; D.cout = cout; D.cin = cin; D.kk2 = kk2;
        D.nt_tot = nt; D.total = nk * nt * 512; D.mode = 0;
        P.d[di++] = D; gt += D.total;
    };
    auto addtw = [&](const float* src, f16* dst, int K) {
        PrepDesc D; D.src = src; D.dst = dst; D.cout = 64; D.cin = 64; D.kk2 = K;
        D.nt_tot = 1; D.total = K * 64; D.mode = 1;
        P.d[di++] = D; gt += D.total;
    };
    addpk(cv1_w,    pcv1, 128, 128, 9,  8, 36);
    addpk(a0_off_w, pa0,  18,  64,  9,  2, 18);
    addpk(a1_off_w, pa1,  50,  64,  25, 4, 50);
    addpk(b0_off_w, pb0,  50,  64,  25, 4, 50);
    addpk(b1_off_w, pb1,  98,  64,  49, 8, 98);
    addpk(conv1_w,  pc1,  64,  64,  1,  4, 2);
    addpk(conv2_w,  pc2,  64,  64,  1,  4, 2);
    addtw(a0_w, dwh_a0, 9);
    addtw(a1_w, dwh_a1, 25);
    addtw(b0_w, dwh_b0, 25);
    addtw(b1_w, dwh_b1, 49);
    P.grand_total = gt;
    prep_k<<<dim3(1024), dim3(256), 0, stream>>>(P);

    auto margs = [&](const f16* in, int cin_tot, int ci_base, const f16* wp, int nt_tot,
                     const float* bias, int cout, int out_stride, int pad, int dil,
                     float* outf, f16* outh) {
        MArgs A;
        A.in = in; A.wp = wp; A.bias = bias; A.outf = outf; A.outh = outh;
        A.bn_g = bn_g; A.bn_b = bn_b; A.bn_m = bn_m; A.bn_v = bn_v; A.zbuf = zbuf;
        A.cin_tot = cin_tot; A.ci_base = ci_base; A.nt_tot = nt_tot; A.cout = cout;
        A.out_stride = out_stride; A.pad = pad; A.dil = dil;
        return A;
    };
    auto dargs = [&](const f16* in, int csh, int ci_base, const float* off, int off_stride,
                     const f16* dwh, f16* outp) {
        DArgs A;
        A.in = in; A.off = off; A.dwh = dwh; A.out = outp;
        A.csh = csh; A.ci_base = ci_base; A.off_stride = off_stride;
        return A;
    };

    // main 3x3 conv + BN + SiLU -> u; 400 px-blocks x 2 col-tiles = 800
    mconv_main_k<<<dim3(800), dim3(256), 0, stream>>>(
        margs(xb, 128, 0, pcv1, 8, nullptr, 128, 128, 1, 1, nullptr, u));

    // offset convs a0 (400) + b0 (400), interleaved 1:1 = 800
    mconv_pair_k<3, 64, 2, 5, 64, 4, 1><<<dim3(800), dim3(256), 0, stream>>>(
        margs(u, 128, 0,  pa0, 2, a0_off_b, 18, 64, 1, 1, offa, nullptr),
        margs(u, 128, 64, pb0, 4, b0_off_b, 50, 64, 2, 1, offb, nullptr));

    // dsample a0 (k3) + b0 (k5): sequential halves
    dsample_pair_k<3, 1, 1, 5, 2, 1><<<dim3(3200), dim3(128), 0, stream>>>(
        dargs(u, 8, 0,  offa, 64, dwh_a0, s0a), 1600,
        dargs(u, 8, 64, offb, 64, dwh_b0, s0b));

    // offset convs a1 (400) + b1 (800: 2 col-tiles), interleaved 1:2 = 1200
    mconv_pair_k<5, 64, 4, 7, 64, 4, 2><<<dim3(1200), dim3(256), 0, stream>>>(
        margs(s0a, 64, 0, pa1, 4, a1_off_b, 50, 64,  6, 3, offa, nullptr),
        margs(s0b, 64, 0, pb1, 8, b1_off_b, 98, 128, 9, 3, offb, nullptr));

    // dsample a1 (k5) + b1 (k7): sequential halves
    dsample_pair_k<5, 6, 3, 7, 9, 3><<<dim3(3200), dim3(128), 0, stream>>>(
        dargs(s0a, 7, 0, offa, 64,  dwh_a1, s1a), 1600,
        dargs(s0b, 7, 0, offb, 128, dwh_b1, s1b));

    // 1x1 convs a (400) + b (400), interleaved 1:1 = 800
    mconv_pair_k<1, 64, 4, 1, 64, 4, 1><<<dim3(800), dim3(256), 0, stream>>>(
        margs(s1a, 64, 0, pc1, 4, conv1_b, 64, 64, 0, 1, aF, nullptr),
        margs(s1b, 64, 0, pc2, 4, conv2_b, 64, 64, 0, 1, bF, nullptr));

    // final: out = x + u * attn
    final_k<<<dim3(BB * HH * 5), dim3(256), 0, stream>>>(x, u, aF, bF, out);
}

// Round 19
// 176.571 us; speedup vs baseline: 1.0884x; 1.0884x over previous
//
#include <hip/hip_runtime.h>

#define HH 80
#define WW 80
#define BB 4
#define NPIX (BB*HH*WW)
#define AS1 __attribute__((address_space(1)))
#define AS3 __attribute__((address_space(3)))

typedef _Float16 f16;
typedef _Float16 f16x8 __attribute__((ext_vector_type(8)));
typedef float    f32x4 __attribute__((ext_vector_type(4)));
typedef unsigned int uint;
typedef unsigned short ushort;

__device__ inline f16x8 splat8(uint u) {
    uint4 q = {u, u, u, u};
    return __builtin_bit_cast(f16x8, q);
}
__device__ inline ushort h_bits(float w) {
    f16 h = (f16)w;
    return __builtin_bit_cast(ushort, h);
}
__device__ inline int swiz200(int m)  { return (m & 7) * 25  + (m >> 3); }
__device__ inline int swiz1600(int m) { return (m & 7) * 200 + (m >> 3); }

// ---------------- fused weight-prep: 7 MFMA-B packs + 4 depthwise f16 transposes --------
struct PrepDesc {
    const float* src; f16* dst;
    int cout, cin, kk2, nt_tot, total, mode;  // mode 0 = MFMA pack, 1 = dwT f16 (kk2 = K)
};
struct PrepArgs { PrepDesc d[11]; int grand_total; };

__global__ void prep_k(PrepArgs P) {
    for (int idx = blockIdx.x * 256 + threadIdx.x; idx < P.grand_total;
         idx += gridDim.x * 256) {
        int i = 0, base = 0;
        while (idx >= base + P.d[i].total) { base += P.d[i].total; i++; }
        const PrepDesc& D = P.d[i];
        int e = idx - base;
        if (D.mode == 0) {
            int j  = e & 7;
            int l  = (e >> 3) & 63;
            int rr = e >> 9;
            int ct = rr % D.nt_tot;
            int ks = rr / D.nt_tot;
            int kkk = ks * 32 + (l >> 4) * 8 + j;
            int tap = kkk / D.cin;
            int ci  = kkk % D.cin;
            int n = ct * 16 + (l & 15);
            float v = (n < D.cout) ? D.src[((size_t)n * D.cin + ci) * D.kk2 + tap] : 0.f;
            D.dst[e] = (f16)v;
        } else {
            int o = e & 63, tt = e >> 6;
            D.dst[e] = (f16)D.src[o * D.kk2 + tt];
        }
    }
}

// ---------------- x (NCHW f32) -> xb (NHWC f16) ----------------
__global__ void xcvt_k(const float* __restrict__ x, f16* __restrict__ xb) {
    __shared__ float l[128 * 17];
    int t = threadIdx.x;
    int blk = blockIdx.x;
    int wb = blk % 5;
    int r  = blk / 5;
    int h  = r % HH;
    int b  = r / HH;
    int w0 = wb * 16;
    size_t pixbase = (size_t)(b * HH + h) * WW + w0;
    for (int e = t; e < 2048; e += 256) {
        int c = e >> 4, p = e & 15;
        l[c * 17 + p] = x[((size_t)(b * 128 + c)) * (HH * WW) + h * WW + w0 + p];
    }
    __syncthreads();
    for (int e = t; e < 2048; e += 256) {
        int c = e & 127, p = e >> 7;
        xb[(pixbase + p) * 128 + c] = (f16)l[c * 17 + p];
    }
}

// ---------------- MFMA implicit-GEMM conv: BM=128, 2-phase gload_lds dbuf (R17) ----------
// FUSE variant (1x1 convs): epilogue computes out = x + u*attn directly (NCHW float4),
// eliminating the separate final_k pass and the attn intermediate buffers.
struct MArgs {
    const f16* in; const f16* wp; const float* bias;
    float* outf; f16* outh;
    const float* bn_g; const float* bn_b; const float* bn_m; const float* bn_v;
    const f16* zbuf;
    int cin_tot, ci_base, nt_tot, cout, out_stride, pad, dil;
    // FUSE-only:
    const float* xres; const f16* ures; float* outp; int outch;
};

template<int K, int CIN, int NT, bool OUT_F16, bool BNSILU, bool FUSE>
__device__ __forceinline__ void mconv_body(int bx, int by, char* lds, const MArgs& A) {
    constexpr int NST  = K * K * CIN / 64;   // stages
    constexpr int AF16 = 8192;               // A f16 per buf (128px x 64ch)
    constexpr int BF16 = NT * 1024;          // B f16 per buf (2 ksteps x NT x 512)
    f16* Al = (f16*)lds;
    f16* Bl = (f16*)(lds + 2 * AF16 * 2);
    const int t    = threadIdx.x;
    const int lane = t & 63;
    const int wv   = t >> 6;
    const int blkpix = bx * 128;
    const int ntb    = by * NT;

    auto stage = [&](int s, int buf) {
        int tap, ch0;
        if constexpr (CIN == 64) { tap = s; ch0 = 0; }
        else                     { tap = s >> 1; ch0 = (s & 1) * 64; }
        int ky = tap / K, kx = tap - ky * K;
        int g    = t & 7;
        int prel = t >> 3;
#pragma unroll
        for (int i = 0; i < 4; i++) {
            int pl  = prel + i * 32;
            int pix = blkpix + pl;
            int b   = pix / 6400;
            int rem = pix - b * 6400;
            int h = rem / WW, w = rem - h * WW;
            int y = h + ky * A.dil - A.pad;
            int x = w + kx * A.dil - A.pad;
            bool v = ((unsigned)y < (unsigned)HH) & ((unsigned)x < (unsigned)WW);
            int sg = g ^ (pl & 7);
            const f16* src = v
                ? A.in + ((size_t)(b * 6400 + y * WW + x)) * A.cin_tot + A.ci_base + ch0 + sg * 8
                : A.zbuf + sg * 8;
            __builtin_amdgcn_global_load_lds((const AS1 void*)src,
                (AS3 void*)(Al + buf * AF16 + i * 2048 + t * 8), 16, 0, 0);
        }
        if constexpr (NT == 4) {
#pragma unroll
            for (int j = 0; j < 2; j++) {
                const f16* src = A.wp + ((size_t)(2 * s + j) * A.nt_tot + ntb) * 512 + t * 8;
                __builtin_amdgcn_global_load_lds((const AS1 void*)src,
                    (AS3 void*)(Bl + buf * BF16 + j * 2048 + t * 8), 16, 0, 0);
            }
        } else {   // NT==2, nt_tot==2, ntb==0
            const f16* src = A.wp + (size_t)(2 * s) * A.nt_tot * 512 + t * 8;
            __builtin_amdgcn_global_load_lds((const AS1 void*)src,
                (AS3 void*)(Bl + buf * BF16 + t * 8), 16, 0, 0);
        }
    };

    f32x4 acc[2][NT];
#pragma unroll
    for (int m = 0; m < 2; m++)
#pragma unroll
        for (int n = 0; n < NT; n++) acc[m][n] = (f32x4){0.f, 0.f, 0.f, 0.f};

    auto compute = [&](int buf) {
#pragma unroll
        for (int j = 0; j < 2; j++) {
            f16x8 bfr[NT];
#pragma unroll
            for (int n = 0; n < NT; n++)
                bfr[n] = *(const f16x8*)(Bl + buf * BF16 + j * NT * 512 + n * 512 + lane * 8);
#pragma unroll
            for (int m = 0; m < 2; m++) {
                int px = wv * 32 + m * 16 + (lane & 15);
                int gi = (j * 4 + (lane >> 4)) ^ (px & 7);
                f16x8 a = *(const f16x8*)(Al + buf * AF16 + px * 64 + gi * 8);
#pragma unroll
                for (int n = 0; n < NT; n++)
                    acc[m][n] = __builtin_amdgcn_mfma_f32_16x16x32_f16(a, bfr[n], acc[m][n], 0, 0, 0);
            }
        }
    };

    stage(0, 0);
    __syncthreads();
    for (int s = 0; s < NST; s++) {
        int buf = s & 1;
        if (s + 1 < NST) stage(s + 1, buf ^ 1);
        compute(buf);
        __syncthreads();
    }

    const int nloc = lane & 15;
#pragma unroll
    for (int m = 0; m < 2; m++) {
        const int prow = blkpix + wv * 32 + m * 16 + (lane >> 4) * 4;
#pragma unroll
        for (int ct = 0; ct < NT; ct++) {
            int n = (ntb + ct) * 16 + nloc;
            if (n >= A.cout) continue;
            float sc = 1.f, sh = 0.f, bv = 0.f;
            if (BNSILU) {
                sc = A.bn_g[n] / sqrtf(A.bn_v[n] + 1e-5f);
                sh = A.bn_b[n] - A.bn_m[n] * sc;
            } else if (A.bias) {
                bv = A.bias[n];
            }
            if constexpr (FUSE) {
                // out = x + u * attn, NCHW float4 (prow % 4 == 0, no batch crossing)
                int c  = A.outch + n;
                int pb = prow / 6400;
                int hw = prow - pb * 6400;
                size_t gi = ((size_t)(pb * 128 + c)) * 6400 + hw;
                float4 xv = *(const float4*)&A.xres[gi];
                const f16* up = A.ures + (size_t)prow * 128 + c;
                float4 ov;
                ov.x = xv.x + (float)up[0]   * (acc[m][ct][0] + bv);
                ov.y = xv.y + (float)up[128] * (acc[m][ct][1] + bv);
                ov.z = xv.z + (float)up[256] * (acc[m][ct][2] + bv);
                ov.w = xv.w + (float)up[384] * (acc[m][ct][3] + bv);
                *(float4*)&A.outp[gi] = ov;
            } else {
#pragma unroll
                for (int r = 0; r < 4; r++) {
                    float vv = acc[m][ct][r] + bv;
                    if (BNSILU) { vv = vv * sc + sh; vv = vv / (1.f + expf(-vv)); }
                    size_t o = (size_t)(prow + r) * A.out_stride + n;
                    if (OUT_F16) A.outh[o] = (f16)vv; else A.outf[o] = vv;
                }
            }
        }
    }
}

__global__ __launch_bounds__(256, 3) void mconv_main_k(MArgs A) {
    __shared__ char lds[2 * 16384 + 2 * 8192];
    int b = blockIdx.x;
    mconv_body<3, 128, 4, true, true, false>(swiz200(b % 200), b / 200, lds, A);
}

// interleaved pair: every (R+1)-th block runs A1
template<int K1, int C1, int N1, int K2, int C2, int N2, int R, bool FUSE>
__global__ __launch_bounds__(256, 3) void mconv_pair_k(MArgs A1, MArgs A2) {
    constexpr int MAXNT = (N1 > N2) ? N1 : N2;
    __shared__ char lds[2 * 16384 + 2 * MAXNT * 2048];
    int b = blockIdx.x;
    int q = b / (R + 1), m = b - q * (R + 1);
    if (m == R) {
        mconv_body<K1, C1, N1, false, false, FUSE>(swiz200(q % 200), q / 200, lds, A1);
    } else {
        int idx = q * R + m;
        mconv_body<K2, C2, N2, false, false, FUSE>(swiz200(idx % 200), idx / 200, lds, A2);
    }
}

// ---------------- deformable sample: R17 body (dw staged in LDS) ----------
struct DArgs {
    const f16* in; const float* off; const f16* dwh; f16* out;
    int csh, ci_base, off_stride;
};
struct alignas(16) DEnt { int o00; short dx1, dy1; uint w01, w23; };

template<int KS, int PAD, int DIL>
__device__ __forceinline__ void dsample_body(int blk, char* ldsraw, const DArgs A) {
    constexpr int K = KS * KS;
    DEnt* ent = (DEnt*)ldsraw;
    f16*  dwl = (f16*)(ldsraw + 16 * K * 16);
    const int t = threadIdx.x;   // 0..127

    for (int e = t; e < 16 * K; e += 128) {
        int p  = e / K;
        int kk = e - p * K;
        int pix = blk * 16 + p;
        int b   = pix / (HH * WW);
        int rem = pix - b * (HH * WW);
        int h   = rem / WW;
        int w   = rem - h * WW;
        int ky = kk / KS, kx = kk - ky * KS;
        float2 d = *(const float2*)&A.off[(size_t)pix * A.off_stride + 2 * kk];
        float py = (float)(h + ky * DIL - PAD) + d.x;
        float px = (float)(w + kx * DIL - PAD) + d.y;
        float y0f = floorf(py), x0f = floorf(px);
        float ty = py - y0f, tx = px - x0f;
        int iy0 = (int)y0f, ix0 = (int)x0f;
        bool vy0 = (unsigned)iy0 < (unsigned)HH;
        bool vy1 = (unsigned)(iy0 + 1) < (unsigned)HH;
        bool vx0 = (unsigned)ix0 < (unsigned)WW;
        bool vx1 = (unsigned)(ix0 + 1) < (unsigned)WW;
        int cy0 = min(max(iy0, 0), HH - 1), cy1 = min(max(iy0 + 1, 0), HH - 1);
        int cx0 = min(max(ix0, 0), WW - 1), cx1 = min(max(ix0 + 1, 0), WW - 1);
        float wy0 = 1.f - ty, wx0 = 1.f - tx;
        ushort w00 = h_bits(wy0 * wx0 * ((vy0 && vx0) ? 1.f : 0.f));
        ushort w01 = h_bits(wy0 * tx  * ((vy0 && vx1) ? 1.f : 0.f));
        ushort w10 = h_bits(ty  * wx0 * ((vy1 && vx0) ? 1.f : 0.f));
        ushort w11 = h_bits(ty  * tx  * ((vy1 && vx1) ? 1.f : 0.f));
        DEnt E;
        E.o00 = (b * (HH * WW) + cy0 * WW + cx0) << A.csh;
        E.dx1 = (short)((cx1 - cx0) << A.csh);
        E.dy1 = (short)(((cy1 - cy0) * WW) << A.csh);
        E.w01 = (uint)w00 | ((uint)w01 << 16);
        E.w23 = (uint)w10 | ((uint)w11 << 16);
        ent[e] = E;
    }
    for (int e = t; e < K * 8; e += 128)
        ((f16x8*)dwl)[e] = ((const f16x8*)A.dwh)[e];
    __syncthreads();

    const int li  = t & 7;
    const int p   = t >> 3;      // 0..15
    const int ch0 = li * 8;
    const int pix = blk * 16 + p;
    const char* ibase = (const char*)(A.in + A.ci_base) + ch0 * 2;
    const f16*  dwb  = dwl + ch0;

    float acc[8];
#pragma unroll
    for (int j = 0; j < 8; j++) acc[j] = 0.f;

#pragma unroll 4
    for (int kk = 0; kk < K; kk++) {
        DEnt e = ent[p * K + kk];
        uint s00 = (e.w01 & 0xffffu) * 0x10001u;
        uint s01 = (e.w01 >> 16)     * 0x10001u;
        uint s10 = (e.w23 & 0xffffu) * 0x10001u;
        uint s11 = (e.w23 >> 16)     * 0x10001u;
        int o00 = e.o00, o01 = o00 + e.dx1, o10 = o00 + e.dy1, o11 = o10 + e.dx1;
        f16x8 c00 = *(const f16x8*)(ibase + o00);
        f16x8 c01 = *(const f16x8*)(ibase + o01);
        f16x8 c10 = *(const f16x8*)(ibase + o10);
        f16x8 c11 = *(const f16x8*)(ibase + o11);
        f16x8 s = c00 * splat8(s00);
        s = c01 * splat8(s01) + s;
        s = c10 * splat8(s10) + s;
        s = c11 * splat8(s11) + s;
        f16x8 dw = *(const f16x8*)(dwb + kk * 64);
#pragma unroll
        for (int j = 0; j < 8; j++)
            acc[j] = fmaf((float)dw[j], (float)s[j], acc[j]);   // v_fma_mix_f32
    }

    f16x8 o;
#pragma unroll
    for (int j = 0; j < 8; j++) o[j] = (f16)acc[j];
    *(f16x8*)&A.out[(size_t)pix * 64 + ch0] = o;
}

// sequential halves: each phase keeps one branch's tensors XCD-resident
template<int K1, int P1, int D1, int K2, int P2, int D2>
__global__ __launch_bounds__(128, 4) void dsample_pair_k(DArgs A1, int nblk1, DArgs A2) {
    constexpr int KMAX = (K1 * K1 > K2 * K2) ? K1 * K1 : K2 * K2;
    __shared__ char lds[16 * KMAX * 16 + KMAX * 128];
    int b = blockIdx.x;
    if (b < nblk1) dsample_body<K1, P1, D1>(swiz1600(b), lds, A1);
    else           dsample_body<K2, P2, D2>(swiz1600(b - nblk1), lds, A2);
}

extern "C" void kernel_launch(void* const* d_in, const int* in_sizes, int n_in,
                              void* d_out, int out_size, void* d_ws, size_t ws_size,
                              hipStream_t stream) {
    const float* x        = (const float*)d_in[0];
    const float* cv1_w    = (const float*)d_in[1];
    const float* bn_g     = (const float*)d_in[2];
    const float* bn_b     = (const float*)d_in[3];
    const float* bn_m     = (const float*)d_in[4];
    const float* bn_v     = (const float*)d_in[5];
    const float* a0_off_w = (const float*)d_in[6];
    const float* a0_off_b = (const float*)d_in[7];
    const float* a0_w     = (const float*)d_in[8];
    const float* a1_off_w = (const float*)d_in[9];
    const float* a1_off_b = (const float*)d_in[10];
    const float* a1_w     = (const float*)d_in[11];
    const float* b0_off_w = (const float*)d_in[12];
    const float* b0_off_b = (const float*)d_in[13];
    const float* b0_w     = (const float*)d_in[14];
    const float* b1_off_w = (const float*)d_in[15];
    const float* b1_off_b = (const float*)d_in[16];
    const float* b1_w     = (const float*)d_in[17];
    const float* conv1_w  = (const float*)d_in[18];
    const float* conv1_b  = (const float*)d_in[19];
    const float* conv2_w  = (const float*)d_in[20];
    const float* conv2_b  = (const float*)d_in[21];
    float* out = (float*)d_out;

    char* wsb = (char*)d_ws;
    size_t pos = 0;
    auto alloc = [&](size_t bytes) -> void* {
        void* p = (void*)(wsb + pos);
        pos += (bytes + 255) & ~(size_t)255;
        return p;
    };
    f16*   zbuf   = (f16*)  alloc(256);
    f16*   xb     = (f16*)  alloc((size_t)NPIX * 128 * 2);
    f16*   u      = (f16*)  alloc((size_t)NPIX * 128 * 2);
    f16*   s0a    = (f16*)  alloc((size_t)NPIX * 64 * 2);
    f16*   s0b    = (f16*)  alloc((size_t)NPIX * 64 * 2);
    f16*   s1a    = (f16*)  alloc((size_t)NPIX * 64 * 2);
    f16*   s1b    = (f16*)  alloc((size_t)NPIX * 64 * 2);
    float* offa   = (float*)alloc((size_t)NPIX * 64 * 4);
    float* offb   = (float*)alloc((size_t)NPIX * 128 * 4);
    f16*   pcv1   = (f16*)  alloc((size_t)36 * 8 * 512 * 2);
    f16*   pa0    = (f16*)  alloc((size_t)18 * 2 * 512 * 2);
    f16*   pa1    = (f16*)  alloc((size_t)50 * 4 * 512 * 2);
    f16*   pb0    = (f16*)  alloc((size_t)50 * 4 * 512 * 2);
    f16*   pb1    = (f16*)  alloc((size_t)98 * 8 * 512 * 2);
    f16*   pc1    = (f16*)  alloc((size_t)2  * 4 * 512 * 2);
    f16*   pc2    = (f16*)  alloc((size_t)2  * 4 * 512 * 2);
    f16*   dwh_a0 = (f16*)  alloc(9  * 64 * 2);
    f16*   dwh_a1 = (f16*)  alloc(25 * 64 * 2);
    f16*   dwh_b0 = (f16*)  alloc(25 * 64 * 2);
    f16*   dwh_b1 = (f16*)  alloc(49 * 64 * 2);

    hipMemsetAsync(zbuf, 0, 256, stream);
    xcvt_k<<<dim3(BB * HH * 5), dim3(256), 0, stream>>>(x, xb);

    // fused weight prep
    PrepArgs P;
    int gt = 0, di = 0;
    auto addpk = [&](const float* src, f16* dst, int cout, int cin, int kk2, int nt, int nk) {
        PrepDesc D; D.src = src; D.dst = dst; D.cout = cout; D.cin = cin; D.kk2 = kk2;
        D.nt_tot = nt; D.total = nk * nt * 512; D.mode = 0;
        P.d[di++] = D; gt += D.total;
    };
    auto addtw = [&](const float* src, f16* dst, int K) {
        PrepDesc D; D.src = src; D.dst = dst; D.cout = 64; D.cin = 64; D.kk2 = K;
        D.nt_tot = 1; D.total = K * 64; D.mode = 1;
        P.d[di++] = D; gt += D.total;
    };
    addpk(cv1_w,    pcv1, 128, 128, 9,  8, 36);
    addpk(a0_off_w, pa0,  18,  64,  9,  2, 18);
    addpk(a1_off_w, pa1,  50,  64,  25, 4, 50);
    addpk(b0_off_w, pb0,  50,  64,  25, 4, 50);
    addpk(b1_off_w, pb1,  98,  64,  49, 8, 98);
    addpk(conv1_w,  pc1,  64,  64,  1,  4, 2);
    addpk(conv2_w,  pc2,  64,  64,  1,  4, 2);
    addtw(a0_w, dwh_a0, 9);
    addtw(a1_w, dwh_a1, 25);
    addtw(b0_w, dwh_b0, 25);
    addtw(b1_w, dwh_b1, 49);
    P.grand_total = gt;
    prep_k<<<dim3(1024), dim3(256), 0, stream>>>(P);

    auto margs = [&](const f16* in, int cin_tot, int ci_base, const f16* wp, int nt_tot,
                     const float* bias, int cout, int out_stride, int pad, int dil,
                     float* outf, f16* outh) {
        MArgs A;
        A.in = in; A.wp = wp; A.bias = bias; A.outf = outf; A.outh = outh;
        A.bn_g = bn_g; A.bn_b = bn_b; A.bn_m = bn_m; A.bn_v = bn_v; A.zbuf = zbuf;
        A.cin_tot = cin_tot; A.ci_base = ci_base; A.nt_tot = nt_tot; A.cout = cout;
        A.out_stride = out_stride; A.pad = pad; A.dil = dil;
        A.xres = nullptr; A.ures = nullptr; A.outp = nullptr; A.outch = 0;
        return A;
    };
    auto dargs = [&](const f16* in, int csh, int ci_base, const float* off, int off_stride,
                     const f16* dwh, f16* outp) {
        DArgs A;
        A.in = in; A.off = off; A.dwh = dwh; A.out = outp;
        A.csh = csh; A.ci_base = ci_base; A.off_stride = off_stride;
        return A;
    };

    // main 3x3 conv + BN + SiLU -> u (f16 NHWC, stride 128); 200 px-blocks x 2 col-tiles
    mconv_main_k<<<dim3(400), dim3(256), 0, stream>>>(
        margs(xb, 128, 0, pcv1, 8, nullptr, 128, 128, 1, 1, nullptr, u));

    // offset convs a0 (NT=2, 200 blk) + b0 (NT=4, 200 blk), interleaved 1:1
    mconv_pair_k<3, 64, 2, 5, 64, 4, 1, false><<<dim3(400), dim3(256), 0, stream>>>(
        margs(u, 128, 0,  pa0, 2, a0_off_b, 18, 64, 1, 1, offa, nullptr),
        margs(u, 128, 64, pb0, 4, b0_off_b, 50, 64, 2, 1, offb, nullptr));

    // dsample a0 (k3) + b0 (k5): sequential halves
    dsample_pair_k<3, 1, 1, 5, 2, 1><<<dim3(3200), dim3(128), 0, stream>>>(
        dargs(u, 8, 0,  offa, 64, dwh_a0, s0a), 1600,
        dargs(u, 8, 64, offb, 64, dwh_b0, s0b));

    // offset convs a1 (k5, 200 blk) + b1 (k7, 400 blk), interleaved 1:2
    mconv_pair_k<5, 64, 4, 7, 64, 4, 2, false><<<dim3(600), dim3(256), 0, stream>>>(
        margs(s0a, 64, 0, pa1, 4, a1_off_b, 50, 64,  6, 3, offa, nullptr),
        margs(s0b, 64, 0, pb1, 8, b1_off_b, 98, 128, 9, 3, offb, nullptr));

    // dsample a1 (k5) + b1 (k7): sequential halves
    dsample_pair_k<5, 6, 3, 7, 9, 3><<<dim3(3200), dim3(128), 0, stream>>>(
        dargs(s0a, 7, 0, offa, 64,  dwh_a1, s1a), 1600,
        dargs(s0b, 7, 0, offb, 128, dwh_b1, s1b));

    // 1x1 convs a + b, FUSED residual epilogue: out = x + u*attn (no final_k pass)
    MArgs F1 = margs(s1a, 64, 0, pc1, 4, conv1_b, 64, 64, 0, 1, nullptr, nullptr);
    F1.xres = x; F1.ures = u; F1.outp = out; F1.outch = 0;
    MArgs F2 = margs(s1b, 64, 0, pc2, 4, conv2_b, 64, 64, 0, 1, nullptr, nullptr);
    F2.xres = x; F2.ures = u; F2.outp = out; F2.outch = 64;
    mconv_pair_k<1, 64, 4, 1, 64, 4, 1, true><<<dim3(400), dim3(256), 0, stream>>>(F1, F2);
}